// Round 8
// baseline (80.088 us; speedup 1.0000x reference)
//
#include <hip/hip_runtime.h>
#include <stdint.h>

// Batched zero-phase Butterworth filtfilt (order 5), rows of length 8192.
// Block = 256 threads, processes ROWS=4 rows through a 2-deep LDS pipeline:
//   issue DMA(row r+2 -> buf[r&1]) while computing row r+1 from buf[(r+1)&1].
// Raw s_barrier + counted s_waitcnt vmcnt(N) keep the global_load_lds DMA in
// flight across barriers (HIP __syncthreads would drain vmcnt(0) -- the R5
// failure). Per-wave VMEM accounting: 8 gload_lds + 8 dwordx4 stores per row.
//
// Per row (R6 numerics, absmax 0.015625): thread owns a 32-sample chunk,
// warms over chunk tid-1 (pole decay 0.819^32 ~ 1.7e-3 << 8.8e-2 threshold),
// y exchanged via LDS for the backward warmup, backward own-chunk from regs.
// LDS quad-XOR layout: quad (c,j) at word 32c + 4*(j^(c&7)); chunk 0 linear
// so the exact edge paths (tid 0 fwd / tid 255 tail+bwd) use scalar access.
// Staging: gload_lds 16B/lane, linear LDS dest + pre-swizzled global source.

#define NN   8192
#define PADL 18
#define LC   32
#define TPB  256
#define ROWS 4

typedef uint32_t u32;

__device__ __forceinline__ void gload16(const float* g, float* l) {
    __builtin_amdgcn_global_load_lds(
        (const __attribute__((address_space(1))) u32*)g,
        (__attribute__((address_space(3))) u32*)l, 16, 0, 0);
}

#define WAITV(N) do { asm volatile("s_waitcnt vmcnt(" #N ")" ::: "memory"); \
                      __builtin_amdgcn_sched_barrier(0); } while (0)
#define WAITL()  do { asm volatile("s_waitcnt lgkmcnt(0)" ::: "memory");    \
                      __builtin_amdgcn_sched_barrier(0); } while (0)
#define BAR()    do { __builtin_amdgcn_sched_barrier(0);                    \
                      __builtin_amdgcn_s_barrier();                         \
                      __builtin_amdgcn_sched_barrier(0); } while (0)

// scalar element e (0..31) of chunk c
__device__ __forceinline__ float SC(const float* b, int c, int e) {
    return b[(c << 5) + (((e >> 2) ^ (c & 7)) << 2) + (e & 3)];
}
// quad j (0..7) of chunk c
__device__ __forceinline__ float4 LDQ(const float* b, int c, int j) {
    return *reinterpret_cast<const float4*>(b + (c << 5) + ((j ^ (c & 7)) << 2));
}
__device__ __forceinline__ void STQ(float* b, int c, int j, float4 v) {
    *reinterpret_cast<float4*>(b + (c << 5) + ((j ^ (c & 7)) << 2)) = v;
}

// one DF2T step; updates z0..z4, sets yv (10 fma + 1 mul)
#define STEP(xv) do {                               \
    float y_ = fmaf(b0, (xv), z0);                  \
    z0 = fmaf(na1, y_, fmaf(b1, (xv), z1));         \
    z1 = fmaf(na2, y_, fmaf(b2, (xv), z2));         \
    z2 = fmaf(na3, y_, fmaf(b3, (xv), z3));         \
    z3 = fmaf(na4, y_, fmaf(b4, (xv), z4));         \
    z4 = fmaf(na5, y_, b5 * (xv));                  \
    yv = y_;                                        \
} while (0)

__global__ __launch_bounds__(TPB, 2) void GREEN_62869731278967_filtfilt(
    const float* __restrict__ x,
    const float* __restrict__ bc,
    const float* __restrict__ ac,
    const float* __restrict__ zc,
    float* __restrict__ out)
{
    __shared__ float lds[2][NN];         // 64 KiB -> 2 blocks/CU
    const int tid = threadIdx.x;
    const int row0 = blockIdx.x * ROWS;
    const int wv = tid >> 6, L = tid & 63;

    const float b0 = bc[0], b1 = bc[1], b2 = bc[2], b3 = bc[3], b4 = bc[4], b5 = bc[5];
    const float na1 = -ac[1], na2 = -ac[2], na3 = -ac[3], na4 = -ac[4], na5 = -ac[5];
    const float zi0 = zc[0], zi1 = zc[1], zi2 = zc[2], zi3 = zc[3], zi4 = zc[4];

    // pre-swizzled per-lane global source offset (see R6 derivation)
    const float* xlane = x + (size_t)row0 * NN
                       + ((wv << 11) + ((L >> 3) << 5) + (((L & 7) ^ (L >> 3)) << 2));

    // ---- prologue: issue DMA for rows 0 and 1 ----
#pragma unroll
    for (int k = 0; k < 8; ++k) gload16(xlane + (k << 8),            &lds[0][(wv << 11) + (k << 8)]);
#pragma unroll
    for (int k = 0; k < 8; ++k) gload16(xlane + NN + (k << 8),       &lds[1][(wv << 11) + (k << 8)]);

#pragma unroll
    for (int r = 0; r < ROWS; ++r) {
        float* B = lds[r & 1];
        float* outr = out + (size_t)(row0 + r) * NN;

        // wait this row's DMA: newer outstanding = loads(r+1) [8 if r==0]
        // or stores(r-1)+loads(r+1) [16 middle] or stores(r-1) [8 last]
        if (r == 0 || r == ROWS - 1) WAITV(8); else WAITV(16);
        BAR();                           // buf[r&1] x ready for all waves

        // ---- forward: warm over chunk tid-1, filter own chunk -> yreg ----
        float yreg[LC];
        float ytail[PADL];               // only tid == 255 uses
        float z0, z1, z2, z3, z4, yv;
        if (tid == 0) {
            const float x0 = B[0];       // chunk 0 is linear
            float v0 = 2.f * x0 - B[PADL];
            z0 = zi0 * v0; z1 = zi1 * v0; z2 = zi2 * v0; z3 = zi3 * v0; z4 = zi4 * v0;
#pragma unroll
            for (int t = 0; t < PADL; ++t) {
                float v = 2.f * x0 - B[PADL - t];
                STEP(v);
            }
        } else {
            float v0 = SC(B, tid - 1, 0);
            z0 = zi0 * v0; z1 = zi1 * v0; z2 = zi2 * v0; z3 = zi3 * v0; z4 = zi4 * v0;
#pragma unroll
            for (int j = 0; j < 8; ++j) {
                float4 q = LDQ(B, tid - 1, j);
                STEP(q.x); STEP(q.y); STEP(q.z); STEP(q.w);
            }
        }
#pragma unroll
        for (int j = 0; j < 8; ++j) {
            float4 q = LDQ(B, tid, j);
            STEP(q.x); yreg[4 * j + 0] = yv;
            STEP(q.y); yreg[4 * j + 1] = yv;
            STEP(q.z); yreg[4 * j + 2] = yv;
            STEP(q.w); yreg[4 * j + 3] = yv;
        }
        if (tid == TPB - 1) {
            const float xN = SC(B, TPB - 1, 31);
#pragma unroll
            for (int i = 0; i < PADL; ++i) {
                float v = 2.f * xN - SC(B, TPB - 1, 30 - i);
                STEP(v);
                ytail[i] = yv;
            }
        }
        BAR();                           // all x reads consumed (data-dep drained)

        // ---- exchange: overwrite chunk tid with y ----
#pragma unroll
        for (int j = 0; j < 8; ++j)
            STQ(B, tid, j, make_float4(yreg[4 * j], yreg[4 * j + 1],
                                       yreg[4 * j + 2], yreg[4 * j + 3]));
        WAITL();                         // y writes committed
        BAR();                           // y visible to all waves

        // ---- backward: warm descending over chunk tid+1's y, own from regs ----
        if (tid == TPB - 1) {
            float u0 = ytail[PADL - 1];
            z0 = zi0 * u0; z1 = zi1 * u0; z2 = zi2 * u0; z3 = zi3 * u0; z4 = zi4 * u0;
#pragma unroll
            for (int s = 0; s < PADL; ++s) STEP(ytail[PADL - 1 - s]);
        } else {
            float u0 = SC(B, tid + 1, LC - 1);
            z0 = zi0 * u0; z1 = zi1 * u0; z2 = zi2 * u0; z3 = zi3 * u0; z4 = zi4 * u0;
#pragma unroll
            for (int j = 7; j >= 0; --j) {
                float4 q = LDQ(B, tid + 1, j);
                STEP(q.w); STEP(q.z); STEP(q.y); STEP(q.x);
            }
        }
#pragma unroll
        for (int i = 0; i < LC; ++i) { STEP(yreg[LC - 1 - i]); yreg[LC - 1 - i] = yv; }

        // ---- store (8x dwordx4; left in flight, counted in vmcnt) ----
#pragma unroll
        for (int q = 0; q < LC / 4; ++q) {
            float4 v;
            v.x = yreg[4 * q + 0];
            v.y = yreg[4 * q + 1];
            v.z = yreg[4 * q + 2];
            v.w = yreg[4 * q + 3];
            *reinterpret_cast<float4*>(outr + tid * LC + 4 * q) = v;
        }

        // ---- issue DMA for row r+2 into this buffer (after all y reads) ----
        if (r + 2 < ROWS) {
            BAR();                       // every wave done reading B
            const float* xn = xlane + (size_t)(r + 2) * NN;
#pragma unroll
            for (int k = 0; k < 8; ++k)
                gload16(xn + (k << 8), &B[(wv << 11) + (k << 8)]);
        }
    }
}

extern "C" void kernel_launch(void* const* d_in, const int* in_sizes, int n_in,
                              void* d_out, int out_size, void* d_ws, size_t ws_size,
                              hipStream_t stream) {
    const float* x  = (const float*)d_in[0];
    const float* b  = (const float*)d_in[1];
    const float* a  = (const float*)d_in[2];
    const float* zi = (const float*)d_in[3];
    float* out = (float*)d_out;
    const int rows = in_sizes[0] / NN;           // 4096
    const int blocks = rows / ROWS;              // 1024
    GREEN_62869731278967_filtfilt<<<blocks, TPB, 0, stream>>>(x, b, a, zi, out);
}

// Round 9
// 72.259 us; speedup vs baseline: 1.1083x; 1.1083x over previous
//
#include <hip/hip_runtime.h>
#include <stdint.h>

// Batched zero-phase Butterworth filtfilt (order 5), rows of length 8192.
// Block = 256 threads processes ROWS=4 rows through a 1.5-deep pipeline in a
// SINGLE 32 KB LDS buffer: x(r) is fully consumed by the forward pass, so the
// DMA for x(r+1) is issued right after the post-forward barrier and streams
// under bwd(r) + stores(r) (counted WAITV, raw s_barrier -- no vmcnt drain).
// y is exchanged via __shfl_down (neighbor chunk = lane+1's registers); only
// the 3 wave-boundary chunks go through a 512 B LDS spare; tid 255 keeps its
// 18-sample tail in registers. 2 barriers/row, 4 blocks/CU preserved.
//
// Numerics (unchanged, absmax 0.015625): thread owns a 32-sample chunk, warms
// over chunk tid-1 (pole decay 0.819^32 ~ 1.7e-3 << 8.8e-2 threshold); edge
// threads (tid 0 fwd, tid 255 tail+bwd) follow the reference exactly.
// LDS quad-XOR layout: quad (c,j) at word 32c + 4*(j^(c&7)); chunk 0 linear.
// Staging: global_load_lds 16B/lane, linear LDS dest + pre-swizzled source.

#define NN   8192
#define PADL 18
#define LC   32
#define TPB  256
#define ROWS 4

typedef uint32_t u32;

__device__ __forceinline__ void gload16(const float* g, float* l) {
    __builtin_amdgcn_global_load_lds(
        (const __attribute__((address_space(1))) u32*)g,
        (__attribute__((address_space(3))) u32*)l, 16, 0, 0);
}

#define WAITV(N) do { asm volatile("s_waitcnt vmcnt(" #N ")" ::: "memory"); \
                      __builtin_amdgcn_sched_barrier(0); } while (0)
#define WAITL()  do { asm volatile("s_waitcnt lgkmcnt(0)" ::: "memory");    \
                      __builtin_amdgcn_sched_barrier(0); } while (0)
#define BAR()    do { __builtin_amdgcn_sched_barrier(0);                    \
                      __builtin_amdgcn_s_barrier();                         \
                      __builtin_amdgcn_sched_barrier(0); } while (0)

// scalar element e (0..31) of chunk c
__device__ __forceinline__ float SC(const float* b, int c, int e) {
    return b[(c << 5) + (((e >> 2) ^ (c & 7)) << 2) + (e & 3)];
}
// quad j (0..7) of chunk c
__device__ __forceinline__ float4 LDQ(const float* b, int c, int j) {
    return *reinterpret_cast<const float4*>(b + (c << 5) + ((j ^ (c & 7)) << 2));
}

// one DF2T step; updates z0..z4, sets yv (10 fma + 1 mul)
#define STEP(xv) do {                               \
    float y_ = fmaf(b0, (xv), z0);                  \
    z0 = fmaf(na1, y_, fmaf(b1, (xv), z1));         \
    z1 = fmaf(na2, y_, fmaf(b2, (xv), z2));         \
    z2 = fmaf(na3, y_, fmaf(b3, (xv), z3));         \
    z3 = fmaf(na4, y_, fmaf(b4, (xv), z4));         \
    z4 = fmaf(na5, y_, b5 * (xv));                  \
    yv = y_;                                        \
} while (0)

__global__ __launch_bounds__(TPB, 4) void GREEN_62869731278967_filtfilt(
    const float* __restrict__ x,
    const float* __restrict__ bc,
    const float* __restrict__ ac,
    const float* __restrict__ zc,
    float* __restrict__ out)
{
    __shared__ float B[NN];              // 32 KiB x buffer (reused every row)
    __shared__ float spare[4 * LC];      // wave-boundary y chunks (512 B)
    const int tid = threadIdx.x;
    const int wv = tid >> 6, L = tid & 63;
    const int row0 = blockIdx.x * ROWS;

    const float b0 = bc[0], b1 = bc[1], b2 = bc[2], b3 = bc[3], b4 = bc[4], b5 = bc[5];
    const float na1 = -ac[1], na2 = -ac[2], na3 = -ac[3], na4 = -ac[4], na5 = -ac[5];
    const float zi0 = zc[0], zi1 = zc[1], zi2 = zc[2], zi3 = zc[3], zi4 = zc[4];

    // pre-swizzled per-lane global source (linear LDS dest = wave base + 16*lane)
    const float* xlane = x + (size_t)row0 * NN
                       + ((wv << 11) + ((L >> 3) << 5) + (((L & 7) ^ (L >> 3)) << 2));
    float* ldst = B + (wv << 11);

    // ---- prologue: issue DMA for row 0 ----
#pragma unroll
    for (int k = 0; k < 8; ++k) gload16(xlane + (k << 8), ldst + (k << 8));

#pragma unroll 1
    for (int r = 0; r < ROWS; ++r) {
        float* outr = out + (size_t)(row0 + r) * NN;

        // wait this row's DMA (newer outstanding: 8 stores of row r-1)
        if (r == 0) WAITV(0); else WAITV(8);
        BAR();                           // x(r) visible to all waves

        // ---- forward: warm over chunk tid-1, filter own chunk -> yreg ----
        float yreg[LC];
        float ytail[PADL];               // only tid == 255 uses
        float z0, z1, z2, z3, z4, yv;
        if (tid == 0) {
            // exact reference path (chunk 0 is linear in LDS)
            const float x0 = B[0];
            float v0 = 2.f * x0 - B[PADL];
            z0 = zi0 * v0; z1 = zi1 * v0; z2 = zi2 * v0; z3 = zi3 * v0; z4 = zi4 * v0;
#pragma unroll
            for (int t = 0; t < PADL; ++t) {
                float v = 2.f * x0 - B[PADL - t];
                STEP(v);
            }
        } else {
            float v0 = SC(B, tid - 1, 0);
            z0 = zi0 * v0; z1 = zi1 * v0; z2 = zi2 * v0; z3 = zi3 * v0; z4 = zi4 * v0;
#pragma unroll
            for (int j = 0; j < 8; ++j) {
                float4 q = LDQ(B, tid - 1, j);
                STEP(q.x); STEP(q.y); STEP(q.z); STEP(q.w);
            }
        }
#pragma unroll
        for (int j = 0; j < 8; ++j) {
            float4 q = LDQ(B, tid, j);
            STEP(q.x); yreg[4 * j + 0] = yv;
            STEP(q.y); yreg[4 * j + 1] = yv;
            STEP(q.z); yreg[4 * j + 2] = yv;
            STEP(q.w); yreg[4 * j + 3] = yv;
        }
        if (tid == TPB - 1) {
            const float xN = SC(B, TPB - 1, 31);
#pragma unroll
            for (int i = 0; i < PADL; ++i) {
                float v = 2.f * xN - SC(B, TPB - 1, 30 - i);
                STEP(v);
                ytail[i] = yv;
            }
        }

        // ---- publish wave-boundary y chunks (producers: tid 64,128,192) ----
        if (L == 0 && wv > 0) {
#pragma unroll
            for (int i = 0; i < LC; ++i) spare[(wv - 1) * LC + i] = yreg[i];
        }
        WAITL();                         // boundary writes committed
        BAR();                           // fwd x-reads done block-wide; spare visible

        // ---- issue DMA for row r+1 into the SAME buffer (x(r) is dead) ----
        if (r + 1 < ROWS) {
            const float* xn = xlane + (size_t)(r + 1) * NN;
#pragma unroll
            for (int k = 0; k < 8; ++k) gload16(xn + (k << 8), ldst + (k << 8));
        }

        // ---- backward warm: chunk tid+1's y via shfl_down (lane 63: spare) ----
        {
            float v = __shfl_down(yreg[LC - 1], 1, 64);
            if (L == 63) v = spare[wv * LC + (LC - 1)];
            z0 = zi0 * v; z1 = zi1 * v; z2 = zi2 * v; z3 = zi3 * v; z4 = zi4 * v;
#pragma unroll
            for (int j = LC - 1; j >= 0; --j) {
                float u = __shfl_down(yreg[j], 1, 64);
                if (L == 63) u = spare[wv * LC + j];
                STEP(u);
            }
        }
        if (tid == TPB - 1) {
            // exact reference path: re-init from in-register tail
            float u0 = ytail[PADL - 1];
            z0 = zi0 * u0; z1 = zi1 * u0; z2 = zi2 * u0; z3 = zi3 * u0; z4 = zi4 * u0;
#pragma unroll
            for (int s = 0; s < PADL; ++s) STEP(ytail[PADL - 1 - s]);
        }

        // ---- backward own chunk (descending, in place) ----
#pragma unroll
        for (int j = LC - 1; j >= 0; --j) { STEP(yreg[j]); yreg[j] = yv; }

        // ---- store (8x dwordx4; drained by next iteration's WAITV(8)) ----
#pragma unroll
        for (int q = 0; q < LC / 4; ++q) {
            float4 v;
            v.x = yreg[4 * q + 0];
            v.y = yreg[4 * q + 1];
            v.z = yreg[4 * q + 2];
            v.w = yreg[4 * q + 3];
            *reinterpret_cast<float4*>(outr + tid * LC + 4 * q) = v;
        }
    }
}

extern "C" void kernel_launch(void* const* d_in, const int* in_sizes, int n_in,
                              void* d_out, int out_size, void* d_ws, size_t ws_size,
                              hipStream_t stream) {
    const float* x  = (const float*)d_in[0];
    const float* b  = (const float*)d_in[1];
    const float* a  = (const float*)d_in[2];
    const float* zi = (const float*)d_in[3];
    float* out = (float*)d_out;
    const int rows = in_sizes[0] / NN;           // 4096
    const int blocks = rows / ROWS;              // 1024
    GREEN_62869731278967_filtfilt<<<blocks, TPB, 0, stream>>>(x, b, a, zi, out);
}